// Round 1
// baseline (383.954 us; speedup 1.0000x reference)
//
#include <hip/hip_runtime.h>

#define DIM 128
#define NUM_OUT 100000

// Kernel 1: per-segment gather + sum.
// segment_ids is sorted, so block s binary-searches its edge range and
// accumulates values[gather_idx[e]][:] into g[s][:]. 64 threads, float2/lane.
__global__ __launch_bounds__(64) void seg_gather_sum(
    const float* __restrict__ values,
    const int* __restrict__ gidx,
    const int* __restrict__ seg,
    float* __restrict__ g,
    int n_edges) {
  const int s = blockIdx.x;

  // lower_bound(seg, s) -> e0 ; lower_bound(seg, s+1) -> e1
  // (all 64 lanes redundantly; uniform branches, broadcast loads)
  int lo = 0, hi = n_edges;
  while (lo < hi) { int m = (lo + hi) >> 1; if (seg[m] < s) lo = m + 1; else hi = m; }
  const int e0 = lo;
  hi = n_edges;
  while (lo < hi) { int m = (lo + hi) >> 1; if (seg[m] < s + 1) lo = m + 1; else hi = m; }
  const int e1 = lo;

  const int t = threadIdx.x;  // 0..63 -> float2 lane
  const float2* __restrict__ v2 = (const float2*)values;

  float accx = 0.f, accy = 0.f;
  int e = e0;
  // unroll x4: 4 independent gather chains in flight
  for (; e + 4 <= e1; e += 4) {
    const int i0 = gidx[e + 0];
    const int i1 = gidx[e + 1];
    const int i2 = gidx[e + 2];
    const int i3 = gidx[e + 3];
    const float2 a = v2[(size_t)i0 * (DIM / 2) + t];
    const float2 b = v2[(size_t)i1 * (DIM / 2) + t];
    const float2 c = v2[(size_t)i2 * (DIM / 2) + t];
    const float2 d = v2[(size_t)i3 * (DIM / 2) + t];
    accx += a.x + b.x + c.x + d.x;
    accy += a.y + b.y + c.y + d.y;
  }
  for (; e < e1; ++e) {
    const float2 a = v2[(size_t)gidx[e] * (DIM / 2) + t];
    accx += a.x;
    accy += a.y;
  }

  float2 r;
  r.x = accx;
  r.y = accy;
  ((float2*)g)[(size_t)s * (DIM / 2) + t] = r;
}

// Kernel 2: y = g @ W, out = tanh(y). W staged in LDS (64 KB) once per block.
// 256 threads: thread -> (row parity, output column f); 64 rows per block.
#define K2_ROWS 64
__global__ __launch_bounds__(256) void gemm_tanh(
    const float* __restrict__ g,
    const float* __restrict__ W,
    float* __restrict__ out,
    int n_rows) {
  __shared__ float Wl[DIM * DIM];
  {
    const float4* __restrict__ W4 = (const float4*)W;
    float4* Wl4 = (float4*)Wl;
    for (int i = threadIdx.x; i < DIM * DIM / 4; i += 256) Wl4[i] = W4[i];
  }
  __syncthreads();

  const int f = threadIdx.x & (DIM - 1);
  const int rs = threadIdx.x >> 7;  // 0 or 1
  const int row0 = blockIdx.x * K2_ROWS;
  const int rend = min(row0 + K2_ROWS, n_rows);

  for (int r = row0 + rs; r < rend; r += 2) {
    const float* __restrict__ gr = g + (size_t)r * DIM;
    float acc = 0.f;
#pragma unroll
    for (int d = 0; d < DIM; d += 4) {
      const float4 gv = *(const float4*)(gr + d);
      acc = fmaf(gv.x, Wl[(d + 0) * DIM + f], acc);
      acc = fmaf(gv.y, Wl[(d + 1) * DIM + f], acc);
      acc = fmaf(gv.z, Wl[(d + 2) * DIM + f], acc);
      acc = fmaf(gv.w, Wl[(d + 3) * DIM + f], acc);
    }
    out[(size_t)r * DIM + f] = tanhf(acc);
  }
}

extern "C" void kernel_launch(void* const* d_in, const int* in_sizes, int n_in,
                              void* d_out, int out_size, void* d_ws, size_t ws_size,
                              hipStream_t stream) {
  const float* values = (const float*)d_in[0];   // [N_SRC, 128] f32
  const float* W      = (const float*)d_in[1];   // [128, 128] f32
  const int*   gidx   = (const int*)d_in[2];     // [E] int
  const int*   seg    = (const int*)d_in[3];     // [E] int, sorted
  float* out = (float*)d_out;                    // [N_OUT, 128] f32
  float* g   = (float*)d_ws;                     // [N_OUT, 128] f32 scratch (51.2 MB)

  const int n_edges = in_sizes[2];

  seg_gather_sum<<<NUM_OUT, 64, 0, stream>>>(values, gidx, seg, g, n_edges);
  gemm_tanh<<<(NUM_OUT + K2_ROWS - 1) / K2_ROWS, 256, 0, stream>>>(g, W, out, NUM_OUT);
}

// Round 2
// 319.057 us; speedup vs baseline: 1.2034x; 1.2034x over previous
//
#include <hip/hip_runtime.h>

#define DIM 128
#define NUM_OUT 100000

__device__ __forceinline__ float fast_tanh(float x) {
  const float xc = fminf(fmaxf(x, -15.f), 15.f);
  const float t = __expf(2.f * xc);
  return __fdividef(t - 1.f, t + 1.f);
}

// Kernel 1: per-segment gather + sum. 128 threads = 2 waves = 2 segments/block.
// segment_ids sorted -> each wave binary-searches its edge range, accumulates
// values[gather_idx[e]][:] with float2 lanes (512 B/row coalesced).
__global__ __launch_bounds__(128) void seg_gather_sum(
    const float* __restrict__ values,
    const int* __restrict__ gidx,
    const int* __restrict__ seg,
    float* __restrict__ g,
    int n_edges) {
  const int s = blockIdx.x * 2 + (threadIdx.x >> 6);
  const int t = threadIdx.x & 63;

  // lower_bound(seg, s) -> e0 ; lower_bound(seg, s+1) -> e1 (wave-uniform)
  int lo = 0, hi = n_edges;
  while (lo < hi) { int m = (lo + hi) >> 1; if (seg[m] < s) lo = m + 1; else hi = m; }
  const int e0 = lo;
  hi = n_edges;
  while (lo < hi) { int m = (lo + hi) >> 1; if (seg[m] < s + 1) lo = m + 1; else hi = m; }
  const int e1 = lo;

  const float2* __restrict__ v2 = (const float2*)values;

  float accx = 0.f, accy = 0.f;
  int e = e0;
  // unroll x8: 8 independent gather rows in flight
  for (; e + 8 <= e1; e += 8) {
    int idx[8];
#pragma unroll
    for (int k = 0; k < 8; ++k) idx[k] = gidx[e + k];
    float2 v[8];
#pragma unroll
    for (int k = 0; k < 8; ++k) v[k] = v2[(size_t)idx[k] * (DIM / 2) + t];
#pragma unroll
    for (int k = 0; k < 8; ++k) { accx += v[k].x; accy += v[k].y; }
  }
  for (; e + 2 <= e1; e += 2) {
    const int i0 = gidx[e + 0];
    const int i1 = gidx[e + 1];
    const float2 a = v2[(size_t)i0 * (DIM / 2) + t];
    const float2 b = v2[(size_t)i1 * (DIM / 2) + t];
    accx += a.x + b.x;
    accy += a.y + b.y;
  }
  if (e < e1) {
    const float2 a = v2[(size_t)gidx[e] * (DIM / 2) + t];
    accx += a.x;
    accy += a.y;
  }

  float2 r;
  r.x = accx;
  r.y = accy;
  ((float2*)g)[(size_t)s * (DIM / 2) + t] = r;
}

// Kernel 2: out = tanh(g @ W). Register-tiled, no LDS.
// 256 threads = 4 waves; wave handles 16 rows (2 half-wave groups of 8),
// 32 lanes x float4 cover all 128 cols. Thread tile: 8 rows x 4 cols.
// W read per-lane (L1/L2-resident, streamed); g read wave-uniform (broadcast).
__global__ __launch_bounds__(256) void gemm_tanh(
    const float* __restrict__ g,
    const float* __restrict__ W,
    float* __restrict__ out,
    int n_rows) {
  const int lane = threadIdx.x & 63;
  const int wv = threadIdx.x >> 6;   // 0..3
  const int h = lane >> 5;           // 0..1
  const int tx = lane & 31;          // 0..31
  const int f = tx * 4;              // output col base
  const int r0 = blockIdx.x * 64 + wv * 16 + h * 8;

  const float* gp[8];
#pragma unroll
  for (int r = 0; r < 8; ++r) {
    int rr = r0 + r;
    rr = rr < n_rows ? rr : n_rows - 1;
    gp[r] = g + (size_t)rr * DIM;
  }

  float acc[8][4] = {};
#pragma unroll 2
  for (int d = 0; d < DIM; d += 2) {
    const float4 w0 = *(const float4*)(W + (d + 0) * DIM + f);
    const float4 w1 = *(const float4*)(W + (d + 1) * DIM + f);
#pragma unroll
    for (int r = 0; r < 8; ++r) {
      const float2 gv = *(const float2*)(gp[r] + d);
      acc[r][0] = fmaf(gv.x, w0.x, acc[r][0]);
      acc[r][1] = fmaf(gv.x, w0.y, acc[r][1]);
      acc[r][2] = fmaf(gv.x, w0.z, acc[r][2]);
      acc[r][3] = fmaf(gv.x, w0.w, acc[r][3]);
      acc[r][0] = fmaf(gv.y, w1.x, acc[r][0]);
      acc[r][1] = fmaf(gv.y, w1.y, acc[r][1]);
      acc[r][2] = fmaf(gv.y, w1.z, acc[r][2]);
      acc[r][3] = fmaf(gv.y, w1.w, acc[r][3]);
    }
  }

#pragma unroll
  for (int r = 0; r < 8; ++r) {
    const int rr = r0 + r;
    if (rr < n_rows) {
      float4 o;
      o.x = fast_tanh(acc[r][0]);
      o.y = fast_tanh(acc[r][1]);
      o.z = fast_tanh(acc[r][2]);
      o.w = fast_tanh(acc[r][3]);
      *(float4*)(out + (size_t)rr * DIM + f) = o;
    }
  }
}

extern "C" void kernel_launch(void* const* d_in, const int* in_sizes, int n_in,
                              void* d_out, int out_size, void* d_ws, size_t ws_size,
                              hipStream_t stream) {
  const float* values = (const float*)d_in[0];   // [N_SRC, 128] f32
  const float* W      = (const float*)d_in[1];   // [128, 128] f32
  const int*   gidx   = (const int*)d_in[2];     // [E] int
  const int*   seg    = (const int*)d_in[3];     // [E] int, sorted
  float* out = (float*)d_out;                    // [N_OUT, 128] f32
  float* g   = (float*)d_ws;                     // [N_OUT, 128] f32 scratch (51.2 MB)

  const int n_edges = in_sizes[2];

  seg_gather_sum<<<NUM_OUT / 2, 128, 0, stream>>>(values, gidx, seg, g, n_edges);
  gemm_tanh<<<(NUM_OUT + 63) / 64, 256, 0, stream>>>(g, W, out, NUM_OUT);
}

// Round 3
// 212.401 us; speedup vs baseline: 1.8077x; 1.5021x over previous
//
#include <hip/hip_runtime.h>

#define DIM 128
#define NUM_OUT 100000
#define OFFS_BYTES (((4 * (NUM_OUT + 1)) + 511) / 512 * 512)

__device__ __forceinline__ float fast_tanh(float x) {
  const float xc = fminf(fmaxf(x, -15.f), 15.f);
  const float t = __expf(2.f * xc);
  return __fdividef(t - 1.f, t + 1.f);
}

// Kernel 0: segment boundaries. offs[s] = first edge e with seg[e] >= s.
// Coalesced O(E); run-starts write their segment (and any empty ones before).
__global__ __launch_bounds__(256) void build_offs(
    const int* __restrict__ seg, int* __restrict__ offs, int n_edges, int n_out) {
  const int e = blockIdx.x * 256 + threadIdx.x;
  if (e >= n_edges) return;
  const int se = seg[e];
  const int sp = (e == 0) ? -1 : seg[e - 1];
  for (int s = sp + 1; s <= se; ++s) offs[s] = e;
  if (e == n_edges - 1) {
    for (int s = se + 1; s <= n_out; ++s) offs[s] = n_edges;
  }
}

// Kernel 1: per-segment gather+sum. 128 threads = 2 waves = 2 segments/block.
// Edge indices for the whole segment loaded in ONE coalesced instruction,
// broadcast to SGPRs via readlane -> scalar-base gathers, 8 in flight.
__global__ __launch_bounds__(128) void seg_gather_sum(
    const float* __restrict__ values,
    const int* __restrict__ gidx,
    const int* __restrict__ offs,
    float* __restrict__ g,
    int n_edges) {
  const int s = blockIdx.x * 2 + (threadIdx.x >> 6);
  const int t = threadIdx.x & 63;

  int e0 = __builtin_amdgcn_readfirstlane(offs[s]);
  int e1 = __builtin_amdgcn_readfirstlane(offs[s + 1]);
  const int len = e1 - e0;

  const float2* __restrict__ v2 = (const float2*)values;
  float accx = 0.f, accy = 0.f;

  for (int base = 0; base < len; base += 64) {
    // one coalesced load covers up to 64 edge indices for this window
    const int my = gidx[min(e0 + base + t, n_edges - 1)];
    const int n = min(64, len - base);
    int k = 0;
    for (; k + 8 <= n; k += 8) {
      int r0 = __builtin_amdgcn_readlane(my, k + 0);
      int r1 = __builtin_amdgcn_readlane(my, k + 1);
      int r2 = __builtin_amdgcn_readlane(my, k + 2);
      int r3 = __builtin_amdgcn_readlane(my, k + 3);
      int r4 = __builtin_amdgcn_readlane(my, k + 4);
      int r5 = __builtin_amdgcn_readlane(my, k + 5);
      int r6 = __builtin_amdgcn_readlane(my, k + 6);
      int r7 = __builtin_amdgcn_readlane(my, k + 7);
      const float2 a0 = v2[(size_t)r0 * (DIM / 2) + t];
      const float2 a1 = v2[(size_t)r1 * (DIM / 2) + t];
      const float2 a2 = v2[(size_t)r2 * (DIM / 2) + t];
      const float2 a3 = v2[(size_t)r3 * (DIM / 2) + t];
      const float2 a4 = v2[(size_t)r4 * (DIM / 2) + t];
      const float2 a5 = v2[(size_t)r5 * (DIM / 2) + t];
      const float2 a6 = v2[(size_t)r6 * (DIM / 2) + t];
      const float2 a7 = v2[(size_t)r7 * (DIM / 2) + t];
      accx += a0.x + a1.x + a2.x + a3.x + a4.x + a5.x + a6.x + a7.x;
      accy += a0.y + a1.y + a2.y + a3.y + a4.y + a5.y + a6.y + a7.y;
    }
    if (k < n) {
      // masked tail of up to 7: clamp to last valid edge (dup line = L1 hit)
      const int nm1 = n - 1;
#pragma unroll
      for (int j = 0; j < 7; j += 4) {
        if (k + j < n) {
          int q0 = __builtin_amdgcn_readlane(my, min(k + j + 0, nm1));
          int q1 = __builtin_amdgcn_readlane(my, min(k + j + 1, nm1));
          int q2 = __builtin_amdgcn_readlane(my, min(k + j + 2, nm1));
          int q3 = __builtin_amdgcn_readlane(my, min(k + j + 3, nm1));
          const float m1 = (k + j + 1 < n) ? 1.f : 0.f;
          const float m2 = (k + j + 2 < n) ? 1.f : 0.f;
          const float m3 = (k + j + 3 < n) ? 1.f : 0.f;
          const float2 b0 = v2[(size_t)q0 * (DIM / 2) + t];
          const float2 b1 = v2[(size_t)q1 * (DIM / 2) + t];
          const float2 b2 = v2[(size_t)q2 * (DIM / 2) + t];
          const float2 b3 = v2[(size_t)q3 * (DIM / 2) + t];
          accx += b0.x + m1 * b1.x + m2 * b2.x + m3 * b3.x;
          accy += b0.y + m1 * b1.y + m2 * b2.y + m3 * b3.y;
        }
      }
    }
  }

  float2 r;
  r.x = accx;
  r.y = accy;
  ((float2*)g)[(size_t)s * (DIM / 2) + t] = r;
}

// Kernel 2: out = tanh(g @ W). Register-tiled, no LDS (unchanged from R2).
__global__ __launch_bounds__(256) void gemm_tanh(
    const float* __restrict__ g,
    const float* __restrict__ W,
    float* __restrict__ out,
    int n_rows) {
  const int lane = threadIdx.x & 63;
  const int wv = threadIdx.x >> 6;   // 0..3
  const int h = lane >> 5;           // 0..1
  const int tx = lane & 31;          // 0..31
  const int f = tx * 4;              // output col base
  const int r0 = blockIdx.x * 64 + wv * 16 + h * 8;

  const float* gp[8];
#pragma unroll
  for (int r = 0; r < 8; ++r) {
    int rr = r0 + r;
    rr = rr < n_rows ? rr : n_rows - 1;
    gp[r] = g + (size_t)rr * DIM;
  }

  float acc[8][4] = {};
#pragma unroll 2
  for (int d = 0; d < DIM; d += 2) {
    const float4 w0 = *(const float4*)(W + (d + 0) * DIM + f);
    const float4 w1 = *(const float4*)(W + (d + 1) * DIM + f);
#pragma unroll
    for (int r = 0; r < 8; ++r) {
      const float2 gv = *(const float2*)(gp[r] + d);
      acc[r][0] = fmaf(gv.x, w0.x, acc[r][0]);
      acc[r][1] = fmaf(gv.x, w0.y, acc[r][1]);
      acc[r][2] = fmaf(gv.x, w0.z, acc[r][2]);
      acc[r][3] = fmaf(gv.x, w0.w, acc[r][3]);
      acc[r][0] = fmaf(gv.y, w1.x, acc[r][0]);
      acc[r][1] = fmaf(gv.y, w1.y, acc[r][1]);
      acc[r][2] = fmaf(gv.y, w1.z, acc[r][2]);
      acc[r][3] = fmaf(gv.y, w1.w, acc[r][3]);
    }
  }

#pragma unroll
  for (int r = 0; r < 8; ++r) {
    const int rr = r0 + r;
    if (rr < n_rows) {
      float4 o;
      o.x = fast_tanh(acc[r][0]);
      o.y = fast_tanh(acc[r][1]);
      o.z = fast_tanh(acc[r][2]);
      o.w = fast_tanh(acc[r][3]);
      *(float4*)(out + (size_t)rr * DIM + f) = o;
    }
  }
}

extern "C" void kernel_launch(void* const* d_in, const int* in_sizes, int n_in,
                              void* d_out, int out_size, void* d_ws, size_t ws_size,
                              hipStream_t stream) {
  const float* values = (const float*)d_in[0];   // [N_SRC, 128] f32
  const float* W      = (const float*)d_in[1];   // [128, 128] f32
  const int*   gidx   = (const int*)d_in[2];     // [E] int
  const int*   seg    = (const int*)d_in[3];     // [E] int, sorted
  float* out = (float*)d_out;                    // [N_OUT, 128] f32

  int*   offs = (int*)d_ws;                          // [N_OUT+1]
  float* g    = (float*)((char*)d_ws + OFFS_BYTES);  // [N_OUT, 128] f32

  const int n_edges = in_sizes[2];

  build_offs<<<(n_edges + 255) / 256, 256, 0, stream>>>(seg, offs, n_edges, NUM_OUT);
  seg_gather_sum<<<NUM_OUT / 2, 128, 0, stream>>>(values, gidx, offs, g, n_edges);
  gemm_tanh<<<(NUM_OUT + 63) / 64, 256, 0, stream>>>(g, W, out, NUM_OUT);
}